// Round 17
// baseline (299.819 us; speedup 1.0000x reference)
//
#include <hip/hip_runtime.h>

#define NTOK  8192
#define NHEAD 16
#define DDIM  128
#define HDIM  384
#define NEXP  8
#define TILE  128
#define ENTRIES 1280   // per-slot work entries (multiple of 8; worst lid = 7+8*142 = 1143)

typedef __attribute__((ext_vector_type(8))) short short8;   // 8 x bf16 (4 VGPRs)
typedef __attribute__((ext_vector_type(4))) float f32x4;    // MFMA accumulator

// ---------------- workspace layout (bytes) ----------------
// wP: chunk-contiguous packed weights: [en(128)][chunk(12)][seg(24)][lane(64)][8]
//   seg 0..7 = W1 (kk=seg>>1, ctg=2*chunk+(seg&1)); 8..15 = Wg; 16..23 = W2 (kk=chunk, ct=seg-16)
#define SZ_WP    (128UL*12*24*512*2)          // 37,748,736
#define OFF_WP   0UL
#define OFF_ROUT (OFF_WP + SZ_WP)             // Routing[8192], 16B each
#define OFF_CNT  (OFF_ROUT + 8192UL*16)       // cnt[16], cur[16]
#define OFF_TAB  (OFF_CNT + 256)              // int4[2][ENTRIES]
#define OFF_LIST (OFF_TAB + 2UL*ENTRIES*16)   // int[2][8192]
#define OFF_WL   (OFF_LIST + 2UL*8192*4)      // float[2][8192]
#define OFF_XB   (OFF_WL + 2UL*8192*4)        // bf16 x copy [tok][2048], 33,554,432 B

struct Routing { int i0, i1; float w0, w1; };

__device__ __forceinline__ unsigned short f2bf(float f) {
  unsigned int u = __float_as_uint(f);
  u += 0x7fffu + ((u >> 16) & 1u);            // round-to-nearest-even
  return (unsigned short)(u >> 16);
}

// async global->LDS DMA, 16B per lane; LDS dest = uniform base + lane*16 (m104)
__device__ __forceinline__ void dma16(const unsigned short* g, char* l) {
  __builtin_amdgcn_global_load_lds(
      (const __attribute__((address_space(1))) unsigned int*)g,
      (__attribute__((address_space(3))) unsigned int*)l, 16, 0, 0);
}

// ---------------- zero out (harness poisons to 0xAA; atomics need 0 base) ----------------
__global__ __launch_bounds__(256) void zero_kernel(float4* __restrict__ out) {
  const int i = blockIdx.x * 256 + threadIdx.x;
  #pragma unroll
  for (int k = 0; k < 8; ++k)
    out[i + k * (2048 * 256)] = make_float4(0.f, 0.f, 0.f, 0.f);
}

// ---------------- weight conversion: fp32 -> bf16 chunk-contiguous frags ----------------
__global__ __launch_bounds__(256) void convA_kernel(
    const float* __restrict__ w1, const float* __restrict__ wg,
    unsigned short* __restrict__ wP) {
  __shared__ float ls[32][388];
  const int kk = blockIdx.x;          // 0..3
  const int en = blockIdx.y;          // 0..127
  const int z  = blockIdx.z;          // 0=W1, 1=Wg
  const float* src = (z == 0 ? w1 : wg) + ((size_t)en * DDIM + kk * 32) * HDIM;
  const int tid = threadIdx.x;
  #pragma unroll
  for (int i = 0; i < 12; ++i) {
    int f4 = i * 256 + tid;           // 3072 float4 = 32x384
    int row = f4 / 96, c4 = f4 % 96;
    float4 v = reinterpret_cast<const float4*>(src + (size_t)row * HDIM)[c4];
    ls[row][c4*4+0] = v.x; ls[row][c4*4+1] = v.y;
    ls[row][c4*4+2] = v.z; ls[row][c4*4+3] = v.w;
  }
  __syncthreads();
  #pragma unroll
  for (int i = 0; i < 6; ++i) {
    int fid = i * 256 + tid;          // 1536 = 24ct * 64lane
    int ct = fid >> 6, lane = fid & 63;
    int r0 = (lane >> 4) * 8, c = ct * 16 + (lane & 15);
    unsigned short o[8];
    #pragma unroll
    for (int j = 0; j < 8; ++j) o[j] = f2bf(ls[r0 + j][c]);
    size_t off = (((size_t)en * 12 + (ct >> 1)) * 24 + (z * 8 + kk * 2 + (ct & 1))) * 512
               + (size_t)lane * 8;
    reinterpret_cast<uint4*>(wP + off)[0] =
        make_uint4((unsigned)o[0] | ((unsigned)o[1] << 16),
                   (unsigned)o[2] | ((unsigned)o[3] << 16),
                   (unsigned)o[4] | ((unsigned)o[5] << 16),
                   (unsigned)o[6] | ((unsigned)o[7] << 16));
  }
}

__global__ __launch_bounds__(256) void convB_kernel(
    const float* __restrict__ w2, unsigned short* __restrict__ wP) {
  __shared__ float ls[32][132];
  const int kk = blockIdx.x;          // 0..11 (= chunk)
  const int en = blockIdx.y;
  const float* src = w2 + ((size_t)en * HDIM + kk * 32) * DDIM;
  const int tid = threadIdx.x;
  #pragma unroll
  for (int i = 0; i < 4; ++i) {
    int f4 = i * 256 + tid;           // 1024 float4 = 32x128
    int row = f4 >> 5, c4 = f4 & 31;
    float4 v = reinterpret_cast<const float4*>(src + (size_t)row * DDIM)[c4];
    ls[row][c4*4+0] = v.x; ls[row][c4*4+1] = v.y;
    ls[row][c4*4+2] = v.z; ls[row][c4*4+3] = v.w;
  }
  __syncthreads();
  #pragma unroll
  for (int i = 0; i < 2; ++i) {
    int fid = i * 256 + tid;          // 512 = 8ct * 64lane
    int ct = fid >> 6, lane = fid & 63;
    int r0 = (lane >> 4) * 8, c = ct * 16 + (lane & 15);
    unsigned short o[8];
    #pragma unroll
    for (int j = 0; j < 8; ++j) o[j] = f2bf(ls[r0 + j][c]);
    size_t off = (((size_t)en * 12 + kk) * 24 + (16 + ct)) * 512 + (size_t)lane * 8;
    reinterpret_cast<uint4*>(wP + off)[0] =
        make_uint4((unsigned)o[0] | ((unsigned)o[1] << 16),
                   (unsigned)o[2] | ((unsigned)o[3] << 16),
                   (unsigned)o[4] | ((unsigned)o[5] << 16),
                   (unsigned)o[6] | ((unsigned)o[7] << 16));
  }
}

// ---------------- router: logits + bf16 x copy (side product) ----------------
__global__ __launch_bounds__(256) void router_kernel(
    const float* __restrict__ x, const float* __restrict__ rw,
    Routing* __restrict__ routing, unsigned short* __restrict__ xb) {
  const int lane = threadIdx.x & 63;
  const int wgid = blockIdx.x * 4 + (threadIdx.x >> 6);
  const int tok0 = wgid * 4;
  float acc[4][8];
  #pragma unroll
  for (int t = 0; t < 4; ++t)
    #pragma unroll
    for (int e = 0; e < 8; ++e) acc[t][e] = 0.f;
  const float4* xr = reinterpret_cast<const float4*>(x);
  const float4* wr = reinterpret_cast<const float4*>(rw);
  #pragma unroll
  for (int c = 0; c < 8; ++c) {
    float4 wv[8];
    #pragma unroll
    for (int e = 0; e < 8; ++e) wv[e] = wr[e * 512 + c * 64 + lane];
    #pragma unroll
    for (int t = 0; t < 4; ++t) {
      float4 xv = xr[(size_t)(tok0 + t) * 512 + c * 64 + lane];
      // side product: bf16 copy of x (same layout), 8B per (c,t,lane)
      unsigned int lo = (unsigned)f2bf(xv.x) | ((unsigned)f2bf(xv.y) << 16);
      unsigned int hi = (unsigned)f2bf(xv.z) | ((unsigned)f2bf(xv.w) << 16);
      *reinterpret_cast<uint2*>(xb + (size_t)(tok0 + t) * 2048 + c * 256 + lane * 4) =
          make_uint2(lo, hi);
      #pragma unroll
      for (int e = 0; e < 8; ++e)
        acc[t][e] += xv.x * wv[e].x + xv.y * wv[e].y + xv.z * wv[e].z + xv.w * wv[e].w;
    }
  }
  #pragma unroll
  for (int t = 0; t < 4; ++t)
    #pragma unroll
    for (int e = 0; e < 8; ++e) {
      acc[t][e] += __shfl_xor(acc[t][e], 1);
      acc[t][e] += __shfl_xor(acc[t][e], 2);
      acc[t][e] += __shfl_xor(acc[t][e], 4);
    }
  const int l3 = lane & 7;
  #pragma unroll
  for (int t = 0; t < 4; ++t) {
    float v0 = (l3 & 1) ? acc[t][1] : acc[t][0];
    float v1 = (l3 & 1) ? acc[t][3] : acc[t][2];
    float v2 = (l3 & 1) ? acc[t][5] : acc[t][4];
    float v3 = (l3 & 1) ? acc[t][7] : acc[t][6];
    float u0 = (l3 & 2) ? v1 : v0;
    float u1 = (l3 & 2) ? v3 : v2;
    float sel = (l3 & 4) ? u1 : u0;
    sel += __shfl_xor(sel, 8);
    sel += __shfl_xor(sel, 16);
    sel += __shfl_xor(sel, 32);
    float le[8];
    #pragma unroll
    for (int e = 0; e < 8; ++e) le[e] = __shfl(sel, e);
    if (lane == 0) {
      int tok = tok0 + t;
      int i0 = 0; float m0 = le[0];
      #pragma unroll
      for (int e = 1; e < 8; ++e) if (le[e] > m0) { m0 = le[e]; i0 = e; }
      int i1 = -1; float m1 = -3.4e38f;
      #pragma unroll
      for (int e = 0; e < 8; ++e) if (e != i0 && le[e] > m1) { m1 = le[e]; i1 = e; }
      float ed = __expf(m1 - m0);
      Routing r; r.i0 = i0; r.i1 = i1;
      r.w0 = 1.f / (1.f + ed); r.w1 = ed / (1.f + ed);
      routing[tok] = r;
    }
  }
}

// ---------------- count: one block per (slot,expert), atomic-free ----------------
__global__ __launch_bounds__(256) void count_kernel(
    const Routing* __restrict__ routing, int* __restrict__ cnt) {
  const int s = blockIdx.x >> 3, e = blockIdx.x & 7;
  const int tid = threadIdx.x;
  int c = 0;
  for (int t = tid; t < NTOK; t += 256) {
    Routing r = routing[t];
    c += ((s == 0 ? r.i0 : r.i1) == e);
  }
  c += __shfl_xor(c, 32); c += __shfl_xor(c, 16); c += __shfl_xor(c, 8);
  c += __shfl_xor(c, 4);  c += __shfl_xor(c, 2);  c += __shfl_xor(c, 1);
  __shared__ int wsum[4];
  if ((tid & 63) == 0) wsum[tid >> 6] = c;
  __syncthreads();
  if (tid == 0) cnt[blockIdx.x] = wsum[0] + wsum[1] + wsum[2] + wsum[3];
}

// ---------------- build: prefix offsets + XCD-grouped work table ----------------
__global__ void build_kernel(const int* __restrict__ cnt, int* __restrict__ cur,
                             int4* __restrict__ table) {
  const int tid = threadIdx.x;
  for (int i = tid; i < 2 * ENTRIES; i += 256)
    table[i] = make_int4(0, 0, 0, 0);
  __syncthreads();
  if (tid < 16) {
    int s = tid >> 3, e = tid & 7;
    int base = 0;
    for (int k = 0; k < e; ++k) base += cnt[s * 8 + k];
    cur[tid] = base;
  }
  __syncthreads();
  if (tid < 16) {                               // one thread per (slot, xcd)
    int s = tid >> 3, xcd = tid & 7;
    int j = 0;
    int base = 0;
    for (int e = 0; e < 8; ++e) {
      int c = cnt[s * 8 + e];
      #pragma unroll
      for (int nn = 0; nn < 2; ++nn) {
        int n = xcd + nn * 8;                   // heads with n%8 == xcd
        for (int t = 0; t < c; t += TILE) {
          int rc = c - t; if (rc > TILE) rc = TILE;
          table[s * ENTRIES + xcd + 8 * j] = make_int4(e, base + t, rc, n);
          ++j;
        }
      }
      base += c;
    }
  }
}

// ---------------- compact: ordered, atomic-free scatter via block scan ----------------
__global__ __launch_bounds__(256) void compact_kernel(
    const Routing* __restrict__ routing, const int* __restrict__ cur,
    int* __restrict__ list, float* __restrict__ wl) {
  const int s = blockIdx.x >> 3, e = blockIdx.x & 7;
  const int tid = threadIdx.x;
  __shared__ int ps[256];
  int myc = 0;
  for (int t = tid; t < NTOK; t += 256) {
    Routing r = routing[t];
    myc += ((s == 0 ? r.i0 : r.i1) == e);
  }
  ps[tid] = myc;
  __syncthreads();
  for (int off = 1; off < 256; off <<= 1) {
    int v = (tid >= off) ? ps[tid - off] : 0;
    __syncthreads();
    ps[tid] += v;
    __syncthreads();
  }
  int base = cur[blockIdx.x] + ps[tid] - myc;
  for (int t = tid; t < NTOK; t += 256) {
    Routing r = routing[t];
    int ei = (s == 0 ? r.i0 : r.i1);
    if (ei == e) {
      list[s * NTOK + base] = t;
      wl[s * NTOK + base] = (s == 0 ? r.w0 : r.w1);
      ++base;
    }
  }
}

// ---------------- fused expert: merged grid, atomicAdd epilogue, bf16 x ----------------
// R16's proven merged pipeline (VGPR~64, 0 conflicts, counted vmcnt(3),
// 2 uncontended atomics/element into pre-zeroed out, deterministic). Change:
// A-frags gather from the router's bf16 x copy -- half the scattered bytes
// (256B vs 512B granules) and half the load instructions; no fp32->bf16 VALU.
__global__ __launch_bounds__(512, 4) void expert_kernel(
    const unsigned short* __restrict__ xb,
    const unsigned short* __restrict__ wP,
    const int* __restrict__ list, const float* __restrict__ wl,
    const int4* __restrict__ table,
    float* __restrict__ out)
{
  extern __shared__ char smem[];
  char* wb  = smem;             // 2 x 24576B weight chunk buffers
  char* pwb = smem + 49152;     // 4 quarters x 2304B P scratch (72B row stride)
  const int big = (blockIdx.x >= ENTRIES) ? 1 : 0;
  const int slot = big;
  const int lid = blockIdx.x - big * ENTRIES;
  const int4 tb = table[slot * ENTRIES + lid];
  const int e = tb.x, rbeg = tb.y, rcnt = tb.z, n = tb.w;
  if (rcnt == 0) return;
  const int* lst = list + slot * NTOK + rbeg;
  const float* wls = wl + slot * NTOK + rbeg;
  const int tid = threadIdx.x;
  const int wid = tid >> 6, lane = tid & 63;
  const int lr = lane & 15, lq = lane >> 4;
  const int tq = wid >> 1, ch = wid & 1;   // token-quarter, col-half
  char* pq = pwb + tq * 2304;
  const f32x4 z4 = {0.f, 0.f, 0.f, 0.f};

  const unsigned short* wsrc = wP + (size_t)(e * NHEAD + n) * (12 * 24 * 512);

  // ---- A-frags: this wave's 32 token rows x 4 k-steps, bf16 gather (16B/load) ----
  short8 a[2][4];
  #pragma unroll
  for (int mi = 0; mi < 2; ++mi) {
    int row = tq * 32 + mi * 16 + lr;
    int tok = (row < rcnt) ? lst[row] : lst[0];   // padded rows: garbage ok (stores guarded)
    const unsigned short* xp = xb + (size_t)tok * 2048 + n * DDIM;
    #pragma unroll
    for (int kk = 0; kk < 4; ++kk)
      a[mi][kk] = *reinterpret_cast<const short8*>(xp + kk * 32 + lq * 8);
  }

  f32x4 acc[2][4];    // out rows (2 mi) x 4 d-col-tiles (persistent)
  #pragma unroll
  for (int mi = 0; mi < 2; ++mi)
    #pragma unroll
    for (int ct = 0; ct < 4; ++ct) acc[mi][ct] = z4;

  // prologue: DMA weight chunk 0 -> buf 0 (3 segs/wave, fire-and-forget)
  #pragma unroll
  for (int i = 0; i < 3; ++i) {
    int seg = wid * 3 + i;
    dma16(wsrc + (size_t)seg * 512 + lane * 8, wb + seg * 1024);
  }

  #pragma unroll
  for (int c = 0; c < 12; ++c) {
    const int p = c & 1;
    char* wbp = wb + p * 24576;

    // barrier A: all waves done reading buf[p^1] (chunk c-1) -> free for DMA
    asm volatile("s_waitcnt lgkmcnt(0)" ::: "memory");
    __builtin_amdgcn_s_barrier();
    __builtin_amdgcn_sched_barrier(0);

    if (c < 11) {
      char* wbn = wb + (p ^ 1) * 24576;
      #pragma unroll
      for (int i = 0; i < 3; ++i) {
        int seg = wid * 3 + i;
        dma16(wsrc + ((size_t)(c + 1) * 24 + seg) * 512 + lane * 8, wbn + seg * 1024);
      }
      asm volatile("s_waitcnt vmcnt(3)" ::: "memory");  // chunk c landed; c+1 in flight
    } else {
      asm volatile("s_waitcnt vmcnt(0)" ::: "memory");
    }
    // barrier B: everyone's chunk-c DMA landed
    __builtin_amdgcn_s_barrier();
    __builtin_amdgcn_sched_barrier(0);

    // ---- stage 1: ctg = 2c+ch: 16 MFMA (2 mi x 4 kk x {W1,Wg}), silu, P ----
    {
      f32x4 ah[2], ag[2];
      ah[0] = ah[1] = z4; ag[0] = ag[1] = z4;
      #pragma unroll
      for (int kk = 0; kk < 4; ++kk) {
        short8 b1 = *reinterpret_cast<const short8*>(wbp + (kk * 2 + ch) * 1024 + lane * 16);
        short8 bg = *reinterpret_cast<const short8*>(wbp + 8192 + (kk * 2 + ch) * 1024 + lane * 16);
        #pragma unroll
        for (int mi = 0; mi < 2; ++mi) {
          ah[mi] = __builtin_amdgcn_mfma_f32_16x16x32_bf16(a[mi][kk], b1, ah[mi], 0, 0, 0);
          ag[mi] = __builtin_amdgcn_mfma_f32_16x16x32_bf16(a[mi][kk], bg, ag[mi], 0, 0, 0);
        }
      }
      #pragma unroll
      for (int mi = 0; mi < 2; ++mi)
        #pragma unroll
        for (int r = 0; r < 4; ++r) {
          float h1 = ah[mi][r], g = ag[mi][r];
          float val = h1 * g * __builtin_amdgcn_rcpf(1.f + __expf(-g));  // silu
          int rowq = mi * 16 + lq * 4 + r;       // row within quarter (0..31)
          int h = ch * 16 + lr;                  // h within chunk (0..31)
          *reinterpret_cast<unsigned short*>(pq + rowq * 72 + h * 2) = f2bf(val);
        }
    }

    // barrier C: both col-half waves' P writes visible to the quarter
    asm volatile("s_waitcnt lgkmcnt(0)" ::: "memory");
    __builtin_amdgcn_s_barrier();
    __builtin_amdgcn_sched_barrier(0);

    // ---- stage 2: acc += P(32h) @ W2 slice; wave owns d-half ch (4 cts) ----
    {
      short8 a2[2];
      #pragma unroll
      for (int mi = 0; mi < 2; ++mi)
        a2[mi] = *reinterpret_cast<const short8*>(pq + (mi * 16 + lr) * 72 + lq * 16);
      #pragma unroll
      for (int ct = 0; ct < 4; ++ct) {
        short8 b = *reinterpret_cast<const short8*>(wbp + (16 + ch * 4 + ct) * 1024 + lane * 16);
        acc[0][ct] = __builtin_amdgcn_mfma_f32_16x16x32_bf16(a2[0], b, acc[0][ct], 0, 0, 0);
        acc[1][ct] = __builtin_amdgcn_mfma_f32_16x16x32_bf16(a2[1], b, acc[1][ct], 0, 0, 0);
      }
    }
  }

  // ---- epilogue: out += w*acc via uncontended atomics (2 adds/element total) ----
  #pragma unroll
  for (int mi = 0; mi < 2; ++mi)
    #pragma unroll
    for (int r = 0; r < 4; ++r) {
      int row = tq * 32 + mi * 16 + lq * 4 + r;
      if (row < rcnt) {
        int tok = lst[row];
        float wt = wls[row];
        float* op = out + ((size_t)tok * NHEAD + n) * DDIM;
        #pragma unroll
        for (int ct = 0; ct < 4; ++ct) {
          int col = (ch * 4 + ct) * 16 + lr;
          atomicAdd(&op[col], acc[mi][ct][r] * wt);
        }
      }
    }
}

extern "C" void kernel_launch(void* const* d_in, const int* in_sizes, int n_in,
                              void* d_out, int out_size, void* d_ws, size_t ws_size,
                              hipStream_t stream) {
  const float* x  = (const float*)d_in[0];
  const float* rw = (const float*)d_in[1];
  const float* w1 = (const float*)d_in[2];
  const float* wg = (const float*)d_in[3];
  const float* w2 = (const float*)d_in[4];
  float* out = (float*)d_out;
  char* ws = (char*)d_ws;

  unsigned short* wP = (unsigned short*)(ws + OFF_WP);
  Routing* routing = (Routing*)(ws + OFF_ROUT);
  int* cnt = (int*)(ws + OFF_CNT);
  int* cur = cnt + 16;
  int4* table = (int4*)(ws + OFF_TAB);
  int* list = (int*)(ws + OFF_LIST);
  float* wl = (float*)(ws + OFF_WL);
  unsigned short* xb = (unsigned short*)(ws + OFF_XB);

  zero_kernel<<<2048, 256, 0, stream>>>(reinterpret_cast<float4*>(out));
  convA_kernel<<<dim3(4, 128, 2), 256, 0, stream>>>(w1, wg, wP);
  convB_kernel<<<dim3(12, 128, 1), 256, 0, stream>>>(w2, wP);
  router_kernel<<<512, 256, 0, stream>>>(x, rw, routing, xb);
  count_kernel<<<16, 256, 0, stream>>>(routing, cnt);
  build_kernel<<<1, 256, 0, stream>>>(cnt, cur, table);
  compact_kernel<<<16, 256, 0, stream>>>(routing, cur, list, wl);
  expert_kernel<<<2 * ENTRIES, 512, 58368, stream>>>(
      xb, wP, list, wl, table, out);
}

// Round 18
// 258.531 us; speedup vs baseline: 1.1597x; 1.1597x over previous
//
#include <hip/hip_runtime.h>

#define NTOK  8192
#define NHEAD 16
#define DDIM  128
#define HDIM  384
#define NEXP  8
#define TILE  128
#define ENTRIES 1280   // per-slot work entries (multiple of 8; worst lid = 7+8*142 = 1143)

typedef __attribute__((ext_vector_type(8))) short short8;   // 8 x bf16 (4 VGPRs)
typedef __attribute__((ext_vector_type(4))) float f32x4;    // MFMA accumulator

// ---------------- workspace layout (bytes) ----------------
// wP: chunk-contiguous packed weights: [en(128)][chunk(12)][seg(24)][lane(64)][8]
//   seg 0..7 = W1 (kk=seg>>1, ctg=2*chunk+(seg&1)); 8..15 = Wg; 16..23 = W2 (kk=chunk, ct=seg-16)
#define SZ_WP    (128UL*12*24*512*2)          // 37,748,736
#define OFF_WP   0UL
#define OFF_ROUT (OFF_WP + SZ_WP)             // Routing[8192], 16B each
#define OFF_CNT  (OFF_ROUT + 8192UL*16)       // cnt[16], cur[16]
#define OFF_TAB  (OFF_CNT + 256)              // int4[2][ENTRIES]
#define OFF_LIST (OFF_TAB + 2UL*ENTRIES*16)   // int[2][8192]
#define OFF_WL   (OFF_LIST + 2UL*8192*4)      // float[2][8192]

struct Routing { int i0, i1; float w0, w1; };

__device__ __forceinline__ unsigned short f2bf(float f) {
  unsigned int u = __float_as_uint(f);
  u += 0x7fffu + ((u >> 16) & 1u);            // round-to-nearest-even
  return (unsigned short)(u >> 16);
}

// async global->LDS DMA, 16B per lane; LDS dest = uniform base + lane*16 (m104)
__device__ __forceinline__ void dma16(const unsigned short* g, char* l) {
  __builtin_amdgcn_global_load_lds(
      (const __attribute__((address_space(1))) unsigned int*)g,
      (__attribute__((address_space(3))) unsigned int*)l, 16, 0, 0);
}

// ---------------- merged prologue: router + convA + convB + zero ----------------
// All four roles have disjoint outputs (routing / wP / out) and no mutual deps,
// so one dispatch overlaps their ~280MB of traffic under a single launch
// umbrella (R13 measured merged grids sustain ~20% higher BW than serial
// dispatches). Router blocks go FIRST so routing[] completes earliest for
// count_kernel. Dynamic LDS = 49,664B (convA's tile); other roles ignore it.
// Block ranges: [0,512) router | [512,1536) convA | [1536,3072) convB |
//               [3072,5120) zero.
__global__ __launch_bounds__(256) void prologue_kernel(
    const float* __restrict__ x, const float* __restrict__ rw,
    const float* __restrict__ w1, const float* __restrict__ wg,
    const float* __restrict__ w2,
    Routing* __restrict__ routing, unsigned short* __restrict__ wP,
    float4* __restrict__ outz) {
  extern __shared__ char sm[];
  const int bid = blockIdx.x;
  const int tid = threadIdx.x;

  if (bid < 512) {
    // ---------------- router role (proven R16 body) ----------------
    const int lane = tid & 63;
    const int wgid = bid * 4 + (tid >> 6);
    const int tok0 = wgid * 4;
    float acc[4][8];
    #pragma unroll
    for (int t = 0; t < 4; ++t)
      #pragma unroll
      for (int e = 0; e < 8; ++e) acc[t][e] = 0.f;
    const float4* xr = reinterpret_cast<const float4*>(x);
    const float4* wr = reinterpret_cast<const float4*>(rw);
    #pragma unroll
    for (int c = 0; c < 8; ++c) {
      float4 wv[8];
      #pragma unroll
      for (int e = 0; e < 8; ++e) wv[e] = wr[e * 512 + c * 64 + lane];
      #pragma unroll
      for (int t = 0; t < 4; ++t) {
        float4 xv = xr[(size_t)(tok0 + t) * 512 + c * 64 + lane];
        #pragma unroll
        for (int e = 0; e < 8; ++e)
          acc[t][e] += xv.x * wv[e].x + xv.y * wv[e].y + xv.z * wv[e].z + xv.w * wv[e].w;
      }
    }
    #pragma unroll
    for (int t = 0; t < 4; ++t)
      #pragma unroll
      for (int e = 0; e < 8; ++e) {
        acc[t][e] += __shfl_xor(acc[t][e], 1);
        acc[t][e] += __shfl_xor(acc[t][e], 2);
        acc[t][e] += __shfl_xor(acc[t][e], 4);
      }
    const int l3 = lane & 7;
    #pragma unroll
    for (int t = 0; t < 4; ++t) {
      float v0 = (l3 & 1) ? acc[t][1] : acc[t][0];
      float v1 = (l3 & 1) ? acc[t][3] : acc[t][2];
      float v2 = (l3 & 1) ? acc[t][5] : acc[t][4];
      float v3 = (l3 & 1) ? acc[t][7] : acc[t][6];
      float u0 = (l3 & 2) ? v1 : v0;
      float u1 = (l3 & 2) ? v3 : v2;
      float sel = (l3 & 4) ? u1 : u0;
      sel += __shfl_xor(sel, 8);
      sel += __shfl_xor(sel, 16);
      sel += __shfl_xor(sel, 32);
      float le[8];
      #pragma unroll
      for (int e = 0; e < 8; ++e) le[e] = __shfl(sel, e);
      if (lane == 0) {
        int tok = tok0 + t;
        int i0 = 0; float m0 = le[0];
        #pragma unroll
        for (int e = 1; e < 8; ++e) if (le[e] > m0) { m0 = le[e]; i0 = e; }
        int i1 = -1; float m1 = -3.4e38f;
        #pragma unroll
        for (int e = 0; e < 8; ++e) if (e != i0 && le[e] > m1) { m1 = le[e]; i1 = e; }
        float ed = __expf(m1 - m0);
        Routing r; r.i0 = i0; r.i1 = i1;
        r.w0 = 1.f / (1.f + ed); r.w1 = ed / (1.f + ed);
        routing[tok] = r;
      }
    }
  } else if (bid < 1536) {
    // ---------------- convA role: w1/wg -> bf16 frags (proven body) ----------------
    const int idx = bid - 512;                // kk(4) x en(128) x z(2)
    const int kk = idx & 3, en = (idx >> 2) & 127, z = idx >> 9;
    float (*ls)[388] = reinterpret_cast<float (*)[388]>(sm);
    const float* src = (z == 0 ? w1 : wg) + ((size_t)en * DDIM + kk * 32) * HDIM;
    #pragma unroll
    for (int i = 0; i < 12; ++i) {
      int f4 = i * 256 + tid;                 // 3072 float4 = 32x384
      int row = f4 / 96, c4 = f4 % 96;
      float4 v = reinterpret_cast<const float4*>(src + (size_t)row * HDIM)[c4];
      ls[row][c4*4+0] = v.x; ls[row][c4*4+1] = v.y;
      ls[row][c4*4+2] = v.z; ls[row][c4*4+3] = v.w;
    }
    __syncthreads();
    #pragma unroll
    for (int i = 0; i < 6; ++i) {
      int fid = i * 256 + tid;                // 1536 = 24ct * 64lane
      int ct = fid >> 6, lane = fid & 63;
      int r0 = (lane >> 4) * 8, c = ct * 16 + (lane & 15);
      unsigned short o[8];
      #pragma unroll
      for (int j = 0; j < 8; ++j) o[j] = f2bf(ls[r0 + j][c]);
      size_t off = (((size_t)en * 12 + (ct >> 1)) * 24 + (z * 8 + kk * 2 + (ct & 1))) * 512
                 + (size_t)lane * 8;
      reinterpret_cast<uint4*>(wP + off)[0] =
          make_uint4((unsigned)o[0] | ((unsigned)o[1] << 16),
                     (unsigned)o[2] | ((unsigned)o[3] << 16),
                     (unsigned)o[4] | ((unsigned)o[5] << 16),
                     (unsigned)o[6] | ((unsigned)o[7] << 16));
    }
  } else if (bid < 3072) {
    // ---------------- convB role: w2 -> bf16 frags (proven body) ----------------
    const int idx = bid - 1536;               // kk(12) x en(128)
    const int kk = idx % 12, en = idx / 12;
    float (*ls)[132] = reinterpret_cast<float (*)[132]>(sm);
    const float* src = w2 + ((size_t)en * HDIM + kk * 32) * DDIM;
    #pragma unroll
    for (int i = 0; i < 4; ++i) {
      int f4 = i * 256 + tid;                 // 1024 float4 = 32x128
      int row = f4 >> 5, c4 = f4 & 31;
      float4 v = reinterpret_cast<const float4*>(src + (size_t)row * DDIM)[c4];
      ls[row][c4*4+0] = v.x; ls[row][c4*4+1] = v.y;
      ls[row][c4*4+2] = v.z; ls[row][c4*4+3] = v.w;
    }
    __syncthreads();
    #pragma unroll
    for (int i = 0; i < 2; ++i) {
      int fid = i * 256 + tid;                // 512 = 8ct * 64lane
      int ct = fid >> 6, lane = fid & 63;
      int r0 = (lane >> 4) * 8, c = ct * 16 + (lane & 15);
      unsigned short o[8];
      #pragma unroll
      for (int j = 0; j < 8; ++j) o[j] = f2bf(ls[r0 + j][c]);
      size_t off = (((size_t)en * 12 + kk) * 24 + (16 + ct)) * 512 + (size_t)lane * 8;
      reinterpret_cast<uint4*>(wP + off)[0] =
          make_uint4((unsigned)o[0] | ((unsigned)o[1] << 16),
                     (unsigned)o[2] | ((unsigned)o[3] << 16),
                     (unsigned)o[4] | ((unsigned)o[5] << 16),
                     (unsigned)o[6] | ((unsigned)o[7] << 16));
    }
  } else {
    // ---------------- zero role: out = 0 (atomics need a zero base) ----------------
    const int i = (bid - 3072) * 256 + tid;
    #pragma unroll
    for (int k = 0; k < 8; ++k)
      outz[i + k * (2048 * 256)] = make_float4(0.f, 0.f, 0.f, 0.f);
  }
}

// ---------------- count: one block per (slot,expert), atomic-free ----------------
__global__ __launch_bounds__(256) void count_kernel(
    const Routing* __restrict__ routing, int* __restrict__ cnt) {
  const int s = blockIdx.x >> 3, e = blockIdx.x & 7;
  const int tid = threadIdx.x;
  int c = 0;
  for (int t = tid; t < NTOK; t += 256) {
    Routing r = routing[t];
    c += ((s == 0 ? r.i0 : r.i1) == e);
  }
  c += __shfl_xor(c, 32); c += __shfl_xor(c, 16); c += __shfl_xor(c, 8);
  c += __shfl_xor(c, 4);  c += __shfl_xor(c, 2);  c += __shfl_xor(c, 1);
  __shared__ int wsum[4];
  if ((tid & 63) == 0) wsum[tid >> 6] = c;
  __syncthreads();
  if (tid == 0) cnt[blockIdx.x] = wsum[0] + wsum[1] + wsum[2] + wsum[3];
}

// ---------------- build: prefix offsets + XCD-grouped work table ----------------
__global__ void build_kernel(const int* __restrict__ cnt, int* __restrict__ cur,
                             int4* __restrict__ table) {
  const int tid = threadIdx.x;
  for (int i = tid; i < 2 * ENTRIES; i += 256)
    table[i] = make_int4(0, 0, 0, 0);
  __syncthreads();
  if (tid < 16) {
    int s = tid >> 3, e = tid & 7;
    int base = 0;
    for (int k = 0; k < e; ++k) base += cnt[s * 8 + k];
    cur[tid] = base;
  }
  __syncthreads();
  if (tid < 16) {                               // one thread per (slot, xcd)
    int s = tid >> 3, xcd = tid & 7;
    int j = 0;
    int base = 0;
    for (int e = 0; e < 8; ++e) {
      int c = cnt[s * 8 + e];
      #pragma unroll
      for (int nn = 0; nn < 2; ++nn) {
        int n = xcd + nn * 8;                   // heads with n%8 == xcd
        for (int t = 0; t < c; t += TILE) {
          int rc = c - t; if (rc > TILE) rc = TILE;
          table[s * ENTRIES + xcd + 8 * j] = make_int4(e, base + t, rc, n);
          ++j;
        }
      }
      base += c;
    }
  }
}

// ---------------- compact: ordered, atomic-free scatter via block scan ----------------
__global__ __launch_bounds__(256) void compact_kernel(
    const Routing* __restrict__ routing, const int* __restrict__ cur,
    int* __restrict__ list, float* __restrict__ wl) {
  const int s = blockIdx.x >> 3, e = blockIdx.x & 7;
  const int tid = threadIdx.x;
  __shared__ int ps[256];
  int myc = 0;
  for (int t = tid; t < NTOK; t += 256) {
    Routing r = routing[t];
    myc += ((s == 0 ? r.i0 : r.i1) == e);
  }
  ps[tid] = myc;
  __syncthreads();
  for (int off = 1; off < 256; off <<= 1) {
    int v = (tid >= off) ? ps[tid - off] : 0;
    __syncthreads();
    ps[tid] += v;
    __syncthreads();
  }
  int base = cur[blockIdx.x] + ps[tid] - myc;
  for (int t = tid; t < NTOK; t += 256) {
    Routing r = routing[t];
    int ei = (s == 0 ? r.i0 : r.i1);
    if (ei == e) {
      list[s * NTOK + base] = t;
      wl[s * NTOK + base] = (s == 0 ? r.w0 : r.w1);
      ++base;
    }
  }
}

// ---------------- fused expert: merged grid, atomicAdd epilogue (R16, proven) ----------------
// Grid = 2*ENTRIES: blocks [0,E) = slot 0, [E,2E) = slot 1 -- merged grid
// sustains ~20% higher BW than serial dispatches (R13 measurement). Epilogue:
// atomicAdd into pre-zeroed out; each element gets EXACTLY TWO adds (unique
// slot-0 block + unique slot-1 block, distinct addresses, uncontended); fp32
// add commutativity makes the result replay-deterministic.
__global__ __launch_bounds__(512, 4) void expert_kernel(
    const float* __restrict__ x,
    const unsigned short* __restrict__ wP,
    const int* __restrict__ list, const float* __restrict__ wl,
    const int4* __restrict__ table,
    float* __restrict__ out)
{
  extern __shared__ char smem[];
  char* wb  = smem;             // 2 x 24576B weight chunk buffers
  char* pwb = smem + 49152;     // 4 quarters x 2304B P scratch (72B row stride)
  const int big = (blockIdx.x >= ENTRIES) ? 1 : 0;
  const int slot = big;
  const int lid = blockIdx.x - big * ENTRIES;
  const int4 tb = table[slot * ENTRIES + lid];
  const int e = tb.x, rbeg = tb.y, rcnt = tb.z, n = tb.w;
  if (rcnt == 0) return;
  const int* lst = list + slot * NTOK + rbeg;
  const float* wls = wl + slot * NTOK + rbeg;
  const int tid = threadIdx.x;
  const int wid = tid >> 6, lane = tid & 63;
  const int lr = lane & 15, lq = lane >> 4;
  const int tq = wid >> 1, ch = wid & 1;   // token-quarter, col-half
  char* pq = pwb + tq * 2304;
  const f32x4 z4 = {0.f, 0.f, 0.f, 0.f};

  const unsigned short* wsrc = wP + (size_t)(e * NHEAD + n) * (12 * 24 * 512);

  // ---- A-frags: this wave's 32 token rows x 4 k-steps, from global (fp32->bf16) ----
  short8 a[2][4];
  #pragma unroll
  for (int mi = 0; mi < 2; ++mi) {
    int row = tq * 32 + mi * 16 + lr;
    int ok = (row < rcnt);
    int tok = ok ? lst[row] : 0;
    const float* xp = x + ((size_t)tok * NHEAD + n) * DDIM;
    #pragma unroll
    for (int kk = 0; kk < 4; ++kk) {
      const float4* q = reinterpret_cast<const float4*>(xp + kk * 32 + lq * 8);
      float4 v0 = q[0], v1 = q[1];
      if (!ok) { v0 = make_float4(0,0,0,0); v1 = make_float4(0,0,0,0); }
      short8 t;
      t[0] = (short)f2bf(v0.x); t[1] = (short)f2bf(v0.y);
      t[2] = (short)f2bf(v0.z); t[3] = (short)f2bf(v0.w);
      t[4] = (short)f2bf(v1.x); t[5] = (short)f2bf(v1.y);
      t[6] = (short)f2bf(v1.z); t[7] = (short)f2bf(v1.w);
      a[mi][kk] = t;
    }
  }

  f32x4 acc[2][4];    // out rows (2 mi) x 4 d-col-tiles (persistent)
  #pragma unroll
  for (int mi = 0; mi < 2; ++mi)
    #pragma unroll
    for (int ct = 0; ct < 4; ++ct) acc[mi][ct] = z4;

  // prologue: DMA weight chunk 0 -> buf 0 (3 segs/wave, fire-and-forget)
  #pragma unroll
  for (int i = 0; i < 3; ++i) {
    int seg = wid * 3 + i;
    dma16(wsrc + (size_t)seg * 512 + lane * 8, wb + seg * 1024);
  }

  #pragma unroll
  for (int c = 0; c < 12; ++c) {
    const int p = c & 1;
    char* wbp = wb + p * 24576;

    // barrier A: all waves done reading buf[p^1] (chunk c-1) -> free for DMA
    asm volatile("s_waitcnt lgkmcnt(0)" ::: "memory");
    __builtin_amdgcn_s_barrier();
    __builtin_amdgcn_sched_barrier(0);

    if (c < 11) {
      char* wbn = wb + (p ^ 1) * 24576;
      #pragma unroll
      for (int i = 0; i < 3; ++i) {
        int seg = wid * 3 + i;
        dma16(wsrc + ((size_t)(c + 1) * 24 + seg) * 512 + lane * 8, wbn + seg * 1024);
      }
      asm volatile("s_waitcnt vmcnt(3)" ::: "memory");  // chunk c landed; c+1 in flight
    } else {
      asm volatile("s_waitcnt vmcnt(0)" ::: "memory");
    }
    // barrier B: everyone's chunk-c DMA landed
    __builtin_amdgcn_s_barrier();
    __builtin_amdgcn_sched_barrier(0);

    // ---- stage 1: ctg = 2c+ch: 16 MFMA (2 mi x 4 kk x {W1,Wg}), silu, P ----
    {
      f32x4 ah[2], ag[2];
      ah[0] = ah[1] = z4; ag[0] = ag[1] = z4;
      #pragma unroll
      for (int kk = 0; kk < 4; ++kk) {
        short8 b1 = *reinterpret_cast<const short8*>(wbp + (kk * 2 + ch) * 1024 + lane * 16);
        short8 bg = *reinterpret_cast<const short8*>(wbp + 8192 + (kk * 2 + ch) * 1024 + lane * 16);
        #pragma unroll
        for (int mi = 0; mi < 2; ++mi) {
          ah[mi] = __builtin_amdgcn_mfma_f32_16x16x32_bf16(a[mi][kk], b1, ah[mi], 0, 0, 0);
          ag[mi] = __builtin_amdgcn_mfma_f32_16x16x32_bf16(a[mi][kk], bg, ag[mi], 0, 0, 0);
        }
      }
      #pragma unroll
      for (int mi = 0; mi < 2; ++mi)
        #pragma unroll
        for (int r = 0; r < 4; ++r) {
          float h1 = ah[mi][r], g = ag[mi][r];
          float val = h1 * g * __builtin_amdgcn_rcpf(1.f + __expf(-g));  // silu
          int rowq = mi * 16 + lq * 4 + r;       // row within quarter (0..31)
          int h = ch * 16 + lr;                  // h within chunk (0..31)
          *reinterpret_cast<unsigned short*>(pq + rowq * 72 + h * 2) = f2bf(val);
        }
    }

    // barrier C: both col-half waves' P writes visible to the quarter
    asm volatile("s_waitcnt lgkmcnt(0)" ::: "memory");
    __builtin_amdgcn_s_barrier();
    __builtin_amdgcn_sched_barrier(0);

    // ---- stage 2: acc += P(32h) @ W2 slice; wave owns d-half ch (4 cts) ----
    {
      short8 a2[2];
      #pragma unroll
      for (int mi = 0; mi < 2; ++mi)
        a2[mi] = *reinterpret_cast<const short8*>(pq + (mi * 16 + lr) * 72 + lq * 16);
      #pragma unroll
      for (int ct = 0; ct < 4; ++ct) {
        short8 b = *reinterpret_cast<const short8*>(wbp + (16 + ch * 4 + ct) * 1024 + lane * 16);
        acc[0][ct] = __builtin_amdgcn_mfma_f32_16x16x32_bf16(a2[0], b, acc[0][ct], 0, 0, 0);
        acc[1][ct] = __builtin_amdgcn_mfma_f32_16x16x32_bf16(a2[1], b, acc[1][ct], 0, 0, 0);
      }
    }
  }

  // ---- epilogue: out += w*acc via uncontended atomics (2 adds/element total) ----
  #pragma unroll
  for (int mi = 0; mi < 2; ++mi)
    #pragma unroll
    for (int r = 0; r < 4; ++r) {
      int row = tq * 32 + mi * 16 + lq * 4 + r;
      if (row < rcnt) {
        int tok = lst[row];
        float wt = wls[row];
        float* op = out + ((size_t)tok * NHEAD + n) * DDIM;
        #pragma unroll
        for (int ct = 0; ct < 4; ++ct) {
          int col = (ch * 4 + ct) * 16 + lr;
          atomicAdd(&op[col], acc[mi][ct][r] * wt);
        }
      }
    }
}

extern "C" void kernel_launch(void* const* d_in, const int* in_sizes, int n_in,
                              void* d_out, int out_size, void* d_ws, size_t ws_size,
                              hipStream_t stream) {
  const float* x  = (const float*)d_in[0];
  const float* rw = (const float*)d_in[1];
  const float* w1 = (const float*)d_in[2];
  const float* wg = (const float*)d_in[3];
  const float* w2 = (const float*)d_in[4];
  float* out = (float*)d_out;
  char* ws = (char*)d_ws;

  unsigned short* wP = (unsigned short*)(ws + OFF_WP);
  Routing* routing = (Routing*)(ws + OFF_ROUT);
  int* cnt = (int*)(ws + OFF_CNT);
  int* cur = cnt + 16;
  int4* table = (int4*)(ws + OFF_TAB);
  int* list = (int*)(ws + OFF_LIST);
  float* wl = (float*)(ws + OFF_WL);

  prologue_kernel<<<5120, 256, 49664, stream>>>(
      x, rw, w1, wg, w2, routing, wP, reinterpret_cast<float4*>(out));
  count_kernel<<<16, 256, 0, stream>>>(routing, cnt);
  build_kernel<<<1, 256, 0, stream>>>(cnt, cur, table);
  compact_kernel<<<16, 256, 0, stream>>>(routing, cur, list, wl);
  expert_kernel<<<2 * ENTRIES, 512, 58368, stream>>>(
      x, wP, list, wl, table, out);
}